// Round 5
// baseline (204.494 us; speedup 1.0000x reference)
//
#include <hip/hip_runtime.h>
#include <math.h>

#define S_LEN 2048
#define DM 1024
#define NH 16
#define DK 64
#define BATCH 2
#define NQ 32          // S_LEN/64 q-tiles
#define MS (BATCH*S_LEN)

typedef __attribute__((ext_vector_type(8))) short bf16x8;
typedef __attribute__((ext_vector_type(4))) float f32x4;
typedef __attribute__((ext_vector_type(16))) float f32x16;
typedef unsigned short u16;
typedef unsigned int u32;

__device__ __forceinline__ u16 f2b(float f) {
  union { float f; u32 u; } x; x.f = f;
  u32 r = x.u + 0x7FFFu + ((x.u >> 16) & 1u);
  return (u16)(r >> 16);
}

__device__ __forceinline__ u32 cvtpk_bf16(float lo, float hi) {
  u32 r;
  asm volatile("v_cvt_pk_bf16_f32 %0, %1, %2" : "=v"(r) : "v"(lo), "v"(hi));
  return r;
}

struct CvtArgs {
  const float* src[7];
  u16* dst[7];
  int n4[7];
};

__global__ void cvt_all(CvtArgs a) {
  const int seg = blockIdx.y;
  const float* __restrict__ in = a.src[seg];
  u16* __restrict__ out = a.dst[seg];
  const int n4 = a.n4[seg];
  int idx = blockIdx.x * blockDim.x + threadIdx.x;
  int stride = gridDim.x * blockDim.x;
  for (int i = idx; i < n4; i += stride) {
    float4 v = ((const float4*)in)[i];
    ushort4 o;
    o.x = f2b(v.x); o.y = f2b(v.y); o.z = f2b(v.z); o.w = f2b(v.w);
    ((ushort4*)out)[i] = o;
  }
}

__device__ __forceinline__ void gload_lds16(const u16* g, u16* l) {
  __builtin_amdgcn_global_load_lds((const __attribute__((address_space(1))) u32*)g,
                                   (__attribute__((address_space(3))) u32*)l, 16, 0, 0);
}

// C[M,N] = A[M,K] * B[N,K]^T   (bf16 in, f32 acc, bf16 or f32 out)
template<bool OUT_BF16, int BM>
__global__ __launch_bounds__(256) void gemm_bt(
    const u16* __restrict__ A, const u16* __restrict__ B,
    void* __restrict__ Cout, int M, int N, int K)
{
  __shared__ u16 lsA[BM*32];
  __shared__ u16 lsB[128*32];
  constexpr int MF = BM / 32;           // M fragments per wave
  const int tid = threadIdx.x;
  const int lane = tid & 63;
  const int wid = tid >> 6;
  const int wr = wid >> 1, wc = wid & 1;
  const int m0 = blockIdx.y * BM, n0 = blockIdx.x * 128;

  f32x4 acc[MF][4];
#pragma unroll
  for (int i = 0; i < MF; ++i)
#pragma unroll
    for (int j = 0; j < 4; ++j) acc[i][j] = (f32x4){0.f, 0.f, 0.f, 0.f};

  const int ntiles = K >> 5;

#pragma unroll
  for (int i = 0; i < BM/64; ++i) {
    int u = tid + i * 256;
    gload_lds16(A + (size_t)(m0 + (u >> 2)) * K + (u & 3) * 8, &lsA[u * 8]);
  }
#pragma unroll
  for (int i = 0; i < 2; ++i) {
    int u = tid + i * 256;
    gload_lds16(B + (size_t)(n0 + (u >> 2)) * K + (u & 3) * 8, &lsB[u * 8]);
  }

  for (int kt = 0; kt < ntiles; ++kt) {
    __syncthreads();
    bf16x8 af[MF], bfr[4];
    const int kOff = (lane >> 4) * 8;
#pragma unroll
    for (int m = 0; m < MF; ++m)
      af[m] = *(const bf16x8*)&lsA[(wr * (BM/2) + m * 16 + (lane & 15)) * 32 + kOff];
#pragma unroll
    for (int n = 0; n < 4; ++n)
      bfr[n] = *(const bf16x8*)&lsB[(wc * 64 + n * 16 + (lane & 15)) * 32 + kOff];
    __syncthreads();
    if (kt + 1 < ntiles) {
      int k0 = (kt + 1) << 5;
#pragma unroll
      for (int i = 0; i < BM/64; ++i) {
        int u = tid + i * 256;
        gload_lds16(A + (size_t)(m0 + (u >> 2)) * K + k0 + (u & 3) * 8, &lsA[u * 8]);
      }
#pragma unroll
      for (int i = 0; i < 2; ++i) {
        int u = tid + i * 256;
        gload_lds16(B + (size_t)(n0 + (u >> 2)) * K + k0 + (u & 3) * 8, &lsB[u * 8]);
      }
    }
#pragma unroll
    for (int m = 0; m < MF; ++m)
#pragma unroll
      for (int n = 0; n < 4; ++n)
        acc[m][n] = __builtin_amdgcn_mfma_f32_16x16x32_bf16(af[m], bfr[n], acc[m][n], 0, 0, 0);
  }

  const int rbase = m0 + wr * (BM/2) + ((lane >> 4) << 2);
  const int cbase = n0 + wc * 64 + (lane & 15);
#pragma unroll
  for (int m = 0; m < MF; ++m)
#pragma unroll
    for (int n = 0; n < 4; ++n)
#pragma unroll
      for (int j = 0; j < 4; ++j) {
        int r = rbase + m * 16 + j;
        int c = cbase + n * 16;
        if (OUT_BF16)
          ((u16*)Cout)[(size_t)r * N + c] = f2b(acc[m][n][j]);
        else
          ((float*)Cout)[(size_t)r * N + c] = acc[m][n][j];
      }
}

// Flash attention, causal, 32x32 MFMA, swapped QK^T, KV-split across wave-pairs.
// One block per (b,h,qtile): 512 threads = 4 pairs; pair p does tiles t≡p (mod 4)
// into private (m,l,O); single-buffered pair-private LDS + reg-staged prefetch
// (swizzled SOURCE + LINEAR dest + swizzled read — rule #21); flash-combine epilogue.
__global__ __launch_bounds__(512, 4) void attn_fwd(
    const u16* __restrict__ Qp, const u16* __restrict__ Kp, const u16* __restrict__ Vt,
    u16* __restrict__ AO)
{
  __shared__ __align__(16) u16 lds_kv[4][2][64 * 64];   // [pair][K/V][64 rows x 64 cols] 64KB
  __shared__ float lds_ml[4][64][2];                    // 2KB
  const int tid = threadIdx.x;
  const int lane = tid & 63;
  const int wv = tid >> 6;          // 0..7
  const int pair = wv >> 1;         // 0..3
  const int wpair = wv & 1;         // wave within pair
  const int ql = lane & 31;
  const int h = lane >> 5;
  const int bid = blockIdx.x;
  const int qt = (NQ - 1) - (bid >> 5);   // LPT: long q-tiles first, spread over XCDs
  const int bh = bid & 31;
  const int b = bh >> 4;
  const int hh = bh & 15;
  const int q0 = qt * 64;
  const size_t baseQK = (size_t)b * S_LEN * DM + hh * DK;
  const size_t baseV  = (size_t)hh * DK * MS + (size_t)b * S_LEN;

  const int qq = wpair * 32 + ql;   // q row within tile (0..63)
  const int qg = q0 + qq;           // global q row
  const int swz = ql & 7;

  // Q fragments (B-operand)
  bf16x8 qf[4];
#pragma unroll
  for (int ks = 0; ks < 4; ++ks)
    qf[ks] = *(const bf16x8*)&Qp[baseQK + (size_t)qg * DM + ks * 16 + h * 8];

  f32x16 ot[2];
#pragma unroll
  for (int n = 0; n < 2; ++n)
#pragma unroll
    for (int r = 0; r < 16; ++r) ot[n][r] = 0.f;
  float mrun = -1e30f, lrun = 0.f;

  // staging: pair's 128 lanes cover K tile (64x64 u16 = 512 chunks) + V tile.
  const int pl = (wpair << 6) | lane;
  uint4 kreg[4], vreg[4];

#define PREFETCH(KV0) do { \
    _Pragma("unroll") \
    for (int j = 0; j < 4; ++j) { \
      int c = j * 128 + pl; \
      int row = c >> 3, c8 = c & 7; \
      int sc = (c8 ^ (row & 7)) * 8; \
      kreg[j] = *(const uint4*)&Kp[baseQK + (size_t)((KV0) + row) * DM + sc]; \
      vreg[j] = *(const uint4*)&Vt[baseV + (size_t)row * MS + (KV0) + sc]; \
    } \
  } while (0)

  const int nIter = (qt + 4) >> 2;       // ceil((qt+1)/4)
  if (pair <= qt) PREFETCH(pair * 64);

  for (int i = 0; i < nIter; ++i) {
    const int tt = i * 4 + pair;
    const bool active = (tt <= qt);
    __syncthreads();                     // all pairs' previous reads done
    if (active) {
      u16* lkd = lds_kv[pair][0];
      u16* lvd = lds_kv[pair][1];
#pragma unroll
      for (int j = 0; j < 4; ++j) {
        int c = j * 128 + pl;
        int row = c >> 3, c8 = c & 7;
        // LINEAR destination (source column was swizzled): LDS[row][c8] = G[row][c8^(row&7)]
        *(uint4*)&lkd[(row * 8 + c8) * 8] = kreg[j];
        *(uint4*)&lvd[(row * 8 + c8) * 8] = vreg[j];
      }
    }
    const int tn = tt + 4;
    if (tn <= qt) PREFETCH(tn * 64);     // flies during compute
    __syncthreads();                     // tiles visible
    if (!active) continue;

    const int kv0 = tt * 64;
    const u16* lkb = lds_kv[pair][0];
    const u16* lvb = lds_kv[pair][1];

    // ---- QK^T (swapped): S^T[kv][q] ----
    f32x16 st[2];
    __builtin_amdgcn_s_setprio(1);
#pragma unroll
    for (int c = 0; c < 2; ++c) {
#pragma unroll
      for (int r = 0; r < 16; ++r) st[c][r] = 0.f;
#pragma unroll
      for (int ks = 0; ks < 4; ++ks) {
        bf16x8 kf = *(const bf16x8*)&lkb[((c << 5) + ql) * 64 + (((2 * ks + h) ^ swz) << 3)];
        st[c] = __builtin_amdgcn_mfma_f32_32x32x16_bf16(kf, qf[ks], st[c], 0, 0, 0);
      }
    }
    __builtin_amdgcn_s_setprio(0);

    // ---- scale + causal mask (diagonal tile only) ----
    const bool diag = (tt == qt);
#pragma unroll
    for (int c = 0; c < 2; ++c)
#pragma unroll
      for (int r = 0; r < 16; ++r) {
        float sv = st[c][r] * 0.125f;
        if (diag) {
          int kvg = kv0 + c * 32 + (r & 3) + 8 * (r >> 2) + 4 * h;
          sv = (kvg <= qg) ? sv : -1e30f;
        }
        st[c][r] = sv;
      }

    // ---- online softmax: per-lane scalar m/l ----
    float mt = st[0][0];
#pragma unroll
    for (int c = 0; c < 2; ++c)
#pragma unroll
      for (int r = 0; r < 16; ++r) mt = fmaxf(mt, st[c][r]);
    mt = fmaxf(mt, __int_as_float(__shfl_xor(__float_as_int(mt), 32, 64)));

    if (!__all(mt <= mrun + 8.0f)) {     // T13 defer-max
      float mnew = fmaxf(mrun, mt);
      float corr = __expf(mrun - mnew);
      lrun *= corr;
#pragma unroll
      for (int n = 0; n < 2; ++n)
#pragma unroll
        for (int r = 0; r < 16; ++r) ot[n][r] *= corr;
      mrun = mnew;
    }

    float ls = 0.f;
#pragma unroll
    for (int c = 0; c < 2; ++c)
#pragma unroll
      for (int r = 0; r < 16; ++r) {
        float p = __expf(st[c][r] - mrun);
        st[c][r] = p;
        ls += p;
      }
    ls += __int_as_float(__shfl_xor(__float_as_int(ls), 32, 64));
    lrun += ls;

    // ---- PV: O^T += V^T * P (pack bf16 + half-swap inline) ----
#pragma unroll
    for (int kst = 0; kst < 4; ++kst) {
      const int c = kst >> 1, k1 = kst & 1;
      u32 pkg[4];
#pragma unroll
      for (int g4 = 0; g4 < 4; ++g4)
        pkg[g4] = cvtpk_bf16(st[c][2 * (4 * k1 + g4)], st[c][2 * (4 * k1 + g4) + 1]);
      u32 w[4];
#pragma unroll
      for (int par = 0; par < 2; ++par) {
        u32 x = pkg[par];
        u32 y = pkg[2 + par];
        u32 tt2 = h ? x : y;
        u32 tp = (u32)__shfl_xor((int)tt2, 32, 64);
        w[par]     = h ? tp : x;
        w[par + 2] = h ? y : tp;
      }
      union { u32 u[4]; bf16x8 v; } pb;
      pb.u[0] = w[0]; pb.u[1] = w[1]; pb.u[2] = w[2]; pb.u[3] = w[3];
      __builtin_amdgcn_s_setprio(1);
#pragma unroll
      for (int n = 0; n < 2; ++n) {
        bf16x8 vf = *(const bf16x8*)&lvb[((n << 5) + ql) * 64 + (((2 * kst + h) ^ swz) << 3)];
        ot[n] = __builtin_amdgcn_mfma_f32_32x32x16_bf16(vf, pb.v, ot[n], 0, 0, 0);
      }
      __builtin_amdgcn_s_setprio(0);
    }
  }

  // ---- flash-combine of 4 pair-partials (reuse staging LDS) ----
  __syncthreads();                       // all pairs done with K/V LDS
  {
    float* comb = (float*)lds_kv[pair];  // 64 d x 64 q f32, q swizzled by d
#pragma unroll
    for (int n = 0; n < 2; ++n)
#pragma unroll
      for (int r = 0; r < 16; ++r) {
        int d = 32 * n + (r & 3) + 8 * (r >> 2) + 4 * h;
        comb[d * 64 + (qq ^ ((d & 7) << 3))] = ot[n][r];
      }
    if (h == 0) { lds_ml[pair][qq][0] = mrun; lds_ml[pair][qq][1] = lrun; }
  }
  __syncthreads();
  {
    const int q = tid >> 3;
    const int d0 = (tid & 7) * 8;
    float m0 = lds_ml[0][q][0], m1 = lds_ml[1][q][0];
    float m2 = lds_ml[2][q][0], m3 = lds_ml[3][q][0];
    float mg = fmaxf(fmaxf(m0, m1), fmaxf(m2, m3));
    float w0 = __expf(m0 - mg), w1 = __expf(m1 - mg);
    float w2 = __expf(m2 - mg), w3 = __expf(m3 - mg);
    float lsum = w0 * lds_ml[0][q][1] + w1 * lds_ml[1][q][1]
               + w2 * lds_ml[2][q][1] + w3 * lds_ml[3][q][1];
    float inv = 1.0f / lsum;
    const float* c0 = (const float*)lds_kv[0];
    const float* c1 = (const float*)lds_kv[1];
    const float* c2 = (const float*)lds_kv[2];
    const float* c3 = (const float*)lds_kv[3];
    u32 o4[4];
#pragma unroll
    for (int ii = 0; ii < 4; ++ii) {
      int da = d0 + 2 * ii, db = da + 1;
      int ia = da * 64 + (q ^ ((da & 7) << 3));
      int ib = db * 64 + (q ^ ((db & 7) << 3));
      float va = w0 * c0[ia] + w1 * c1[ia] + w2 * c2[ia] + w3 * c3[ia];
      float vb = w0 * c0[ib] + w1 * c1[ib] + w2 * c2[ib] + w3 * c3[ib];
      o4[ii] = cvtpk_bf16(va * inv, vb * inv);
    }
    uint4 outv;
    outv.x = o4[0]; outv.y = o4[1]; outv.z = o4[2]; outv.w = o4[3];
    *(uint4*)&AO[baseQK + (size_t)(q0 + q) * DM + d0] = outv;
  }
#undef PREFETCH
}

extern "C" void kernel_launch(void* const* d_in, const int* in_sizes, int n_in,
                              void* d_out, int out_size, void* d_ws, size_t ws_size,
                              hipStream_t stream) {
  const float* q  = (const float*)d_in[0];
  const float* k  = (const float*)d_in[1];
  const float* v  = (const float*)d_in[2];
  // d_in[3] = mask : deterministic causal tril, applied analytically
  const float* wq = (const float*)d_in[4];
  const float* wk = (const float*)d_in[5];
  const float* wv = (const float*)d_in[6];
  const float* wo = (const float*)d_in[7];

  const size_t nIn = (size_t)MS * DM;
  const size_t nW  = (size_t)DM * DM;

  u16* ws = (u16*)d_ws;
  u16* qb  = ws; ws += nIn;
  u16* kb  = ws; ws += nIn;
  u16* vb  = ws; ws += nIn;
  u16* wqb = ws; ws += nW;
  u16* wkb = ws; ws += nW;
  u16* wvb = ws; ws += nW;
  u16* wob = ws; ws += nW;
  u16* Qp  = ws; ws += nIn;
  u16* Kp  = ws; ws += nIn;
  u16* Vt  = ws; ws += nIn;   // [DM][MS] transposed V projection
  u16* AO  = ws; ws += nIn;

  CvtArgs ca;
  ca.src[0] = q;  ca.dst[0] = qb;  ca.n4[0] = (int)(nIn / 4);
  ca.src[1] = k;  ca.dst[1] = kb;  ca.n4[1] = (int)(nIn / 4);
  ca.src[2] = v;  ca.dst[2] = vb;  ca.n4[2] = (int)(nIn / 4);
  ca.src[3] = wq; ca.dst[3] = wqb; ca.n4[3] = (int)(nW / 4);
  ca.src[4] = wk; ca.dst[4] = wkb; ca.n4[4] = (int)(nW / 4);
  ca.src[5] = wv; ca.dst[5] = wvb; ca.n4[5] = (int)(nW / 4);
  ca.src[6] = wo; ca.dst[6] = wob; ca.n4[6] = (int)(nW / 4);
  cvt_all<<<dim3(256, 7), 256, 0, stream>>>(ca);

  gemm_bt<true,64><<<dim3(8, 64), 256, 0, stream>>>(qb, wqb, Qp, MS, DM, DM);
  gemm_bt<true,64><<<dim3(8, 64), 256, 0, stream>>>(kb, wkb, Kp, MS, DM, DM);
  // V^T = Wv * X^T  -> [DM][MS], the layout attention wants
  gemm_bt<true,64><<<dim3(32, 16), 256, 0, stream>>>(wvb, vb, Vt, DM, MS, DM);

  attn_fwd<<<dim3(NQ * 32), 512, 0, stream>>>(Qp, Kp, Vt, AO);

  gemm_bt<false,64><<<dim3(8, 64), 256, 0, stream>>>(AO, wob, d_out, MS, DM, DM);
}

// Round 6
// 157.386 us; speedup vs baseline: 1.2993x; 1.2993x over previous
//
#include <hip/hip_runtime.h>
#include <math.h>

#define S_LEN 2048
#define DM 1024
#define NH 16
#define DK 64
#define BATCH 2
#define NQ 32          // S_LEN/64 q-tiles
#define MS (BATCH*S_LEN)

typedef __attribute__((ext_vector_type(8))) short bf16x8;
typedef __attribute__((ext_vector_type(4))) float f32x4;
typedef __attribute__((ext_vector_type(16))) float f32x16;
typedef unsigned short u16;
typedef unsigned int u32;

__device__ __forceinline__ u16 f2b(float f) {
  union { float f; u32 u; } x; x.f = f;
  u32 r = x.u + 0x7FFFu + ((x.u >> 16) & 1u);
  return (u16)(r >> 16);
}

__device__ __forceinline__ u32 cvtpk_bf16(float lo, float hi) {
  u32 r;
  asm volatile("v_cvt_pk_bf16_f32 %0, %1, %2" : "=v"(r) : "v"(lo), "v"(hi));
  return r;
}

struct CvtArgs {
  const float* src[7];
  u16* dst[7];
  int n4[7];
};

__global__ void cvt_all(CvtArgs a) {
  const int seg = blockIdx.y;
  const float* __restrict__ in = a.src[seg];
  u16* __restrict__ out = a.dst[seg];
  const int n4 = a.n4[seg];
  int idx = blockIdx.x * blockDim.x + threadIdx.x;
  int stride = gridDim.x * blockDim.x;
  for (int i = idx; i < n4; i += stride) {
    float4 v = ((const float4*)in)[i];
    ushort4 o;
    o.x = f2b(v.x); o.y = f2b(v.y); o.z = f2b(v.z); o.w = f2b(v.w);
    ((ushort4*)out)[i] = o;
  }
}

__device__ __forceinline__ void gload_lds16(const u16* g, u16* l) {
  __builtin_amdgcn_global_load_lds((const __attribute__((address_space(1))) u32*)g,
                                   (__attribute__((address_space(3))) u32*)l, 16, 0, 0);
}

// C[M,N] = A[M,K] * B[N,K]^T   (bf16 in, f32 acc, bf16 or f32 out)
template<bool OUT_BF16, int BM>
__global__ __launch_bounds__(256) void gemm_bt(
    const u16* __restrict__ A, const u16* __restrict__ B,
    void* __restrict__ Cout, int M, int N, int K)
{
  __shared__ u16 lsA[BM*32];
  __shared__ u16 lsB[128*32];
  constexpr int MF = BM / 32;           // M fragments per wave
  const int tid = threadIdx.x;
  const int lane = tid & 63;
  const int wid = tid >> 6;
  const int wr = wid >> 1, wc = wid & 1;
  const int m0 = blockIdx.y * BM, n0 = blockIdx.x * 128;

  f32x4 acc[MF][4];
#pragma unroll
  for (int i = 0; i < MF; ++i)
#pragma unroll
    for (int j = 0; j < 4; ++j) acc[i][j] = (f32x4){0.f, 0.f, 0.f, 0.f};

  const int ntiles = K >> 5;

#pragma unroll
  for (int i = 0; i < BM/64; ++i) {
    int u = tid + i * 256;
    gload_lds16(A + (size_t)(m0 + (u >> 2)) * K + (u & 3) * 8, &lsA[u * 8]);
  }
#pragma unroll
  for (int i = 0; i < 2; ++i) {
    int u = tid + i * 256;
    gload_lds16(B + (size_t)(n0 + (u >> 2)) * K + (u & 3) * 8, &lsB[u * 8]);
  }

  for (int kt = 0; kt < ntiles; ++kt) {
    __syncthreads();
    bf16x8 af[MF], bfr[4];
    const int kOff = (lane >> 4) * 8;
#pragma unroll
    for (int m = 0; m < MF; ++m)
      af[m] = *(const bf16x8*)&lsA[(wr * (BM/2) + m * 16 + (lane & 15)) * 32 + kOff];
#pragma unroll
    for (int n = 0; n < 4; ++n)
      bfr[n] = *(const bf16x8*)&lsB[(wc * 64 + n * 16 + (lane & 15)) * 32 + kOff];
    __syncthreads();
    if (kt + 1 < ntiles) {
      int k0 = (kt + 1) << 5;
#pragma unroll
      for (int i = 0; i < BM/64; ++i) {
        int u = tid + i * 256;
        gload_lds16(A + (size_t)(m0 + (u >> 2)) * K + k0 + (u & 3) * 8, &lsA[u * 8]);
      }
#pragma unroll
      for (int i = 0; i < 2; ++i) {
        int u = tid + i * 256;
        gload_lds16(B + (size_t)(n0 + (u >> 2)) * K + k0 + (u & 3) * 8, &lsB[u * 8]);
      }
    }
#pragma unroll
    for (int m = 0; m < MF; ++m)
#pragma unroll
      for (int n = 0; n < 4; ++n)
        acc[m][n] = __builtin_amdgcn_mfma_f32_16x16x32_bf16(af[m], bfr[n], acc[m][n], 0, 0, 0);
  }

  const int rbase = m0 + wr * (BM/2) + ((lane >> 4) << 2);
  const int cbase = n0 + wc * 64 + (lane & 15);
#pragma unroll
  for (int m = 0; m < MF; ++m)
#pragma unroll
    for (int n = 0; n < 4; ++n)
#pragma unroll
      for (int j = 0; j < 4; ++j) {
        int r = rbase + m * 16 + j;
        int c = cbase + n * 16;
        if (OUT_BF16)
          ((u16*)Cout)[(size_t)r * N + c] = f2b(acc[m][n][j]);
        else
          ((float*)Cout)[(size_t)r * N + c] = acc[m][n][j];
      }
}

// Flash attention, causal, 32x32 MFMA, swapped QK^T, KV-split across wave-pairs.
// One block per (b,h,qtile): 512 threads = 4 pairs; pair p does tiles t≡p (mod 4)
// into private (m,l,O). Staging via global_load_lds: pre-swizzled GLOBAL source +
// linear LDS dest + swizzled read (R3-verified pattern, rule #21). No reg staging
// -> no spill. Flash-combine epilogue in LDS.
__global__ __launch_bounds__(512, 2) void attn_fwd(
    const u16* __restrict__ Qp, const u16* __restrict__ Kp, const u16* __restrict__ Vt,
    u16* __restrict__ AO)
{
  __shared__ __align__(16) u16 lds_kv[4][2][64 * 64];   // [pair][K/V][64 rows x 64 cols] 64KB
  __shared__ float lds_ml[4][64][2];                    // 2KB
  const int tid = threadIdx.x;
  const int lane = tid & 63;
  const int wv = tid >> 6;          // 0..7
  const int pair = wv >> 1;         // 0..3
  const int wpair = wv & 1;         // wave within pair
  const int ql = lane & 31;
  const int h = lane >> 5;
  const int bid = blockIdx.x;
  const int qt = (NQ - 1) - (bid >> 5);   // LPT: long q-tiles first, spread over XCDs
  const int bh = bid & 31;
  const int b = bh >> 4;
  const int hh = bh & 15;
  const int q0 = qt * 64;
  const size_t baseQK = (size_t)b * S_LEN * DM + hh * DK;
  const size_t baseV  = (size_t)hh * DK * MS + (size_t)b * S_LEN;

  const int qq = wpair * 32 + ql;   // q row within tile (0..63)
  const int qg = q0 + qq;           // global q row
  const int swz = ql & 7;

  // Q fragments (B-operand)
  bf16x8 qf[4];
#pragma unroll
  for (int ks = 0; ks < 4; ++ks)
    qf[ks] = *(const bf16x8*)&Qp[baseQK + (size_t)qg * DM + ks * 16 + h * 8];

  f32x16 ot[2];
#pragma unroll
  for (int n = 0; n < 2; ++n)
#pragma unroll
    for (int r = 0; r < 16; ++r) ot[n][r] = 0.f;
  float mrun = -1e30f, lrun = 0.f;

  // staging: pair's 128 lanes cover K tile (64x64 u16 = 512 16B-chunks) + V tile.
  // chunk c -> row=c>>3, c8=c&7; source col swizzled, LDS dest linear (lane-ordered).
  const int pl = (wpair << 6) | lane;
  u16* const lkd = lds_kv[pair][0];
  u16* const lvd = lds_kv[pair][1];

#define STAGE_PAIR(KV0) do { \
    _Pragma("unroll") \
    for (int j = 0; j < 4; ++j) { \
      int c = j * 128 + pl; \
      int row = c >> 3, c8 = c & 7; \
      int sc = (c8 ^ (row & 7)) * 8; \
      gload_lds16(Kp + baseQK + (size_t)((KV0) + row) * DM + sc, &lkd[c * 8]); \
      gload_lds16(Vt + baseV + (size_t)row * MS + (KV0) + sc, &lvd[c * 8]); \
    } \
  } while (0)

  const int nIter = (qt + 4) >> 2;       // ceil((qt+1)/4)

  for (int i = 0; i < nIter; ++i) {
    const int tt = i * 4 + pair;
    const bool active = (tt <= qt);
    __syncthreads();                     // all pairs' previous-iter reads done
    if (active) STAGE_PAIR(tt * 64);
    __syncthreads();                     // vmcnt drained -> tiles visible
    if (!active) continue;

    const int kv0 = tt * 64;
    const u16* lkb = lkd;
    const u16* lvb = lvd;

    // ---- QK^T (swapped): S^T[kv][q] ----
    f32x16 st[2];
    __builtin_amdgcn_s_setprio(1);
#pragma unroll
    for (int c = 0; c < 2; ++c) {
#pragma unroll
      for (int r = 0; r < 16; ++r) st[c][r] = 0.f;
#pragma unroll
      for (int ks = 0; ks < 4; ++ks) {
        bf16x8 kf = *(const bf16x8*)&lkb[((c << 5) + ql) * 64 + (((2 * ks + h) ^ swz) << 3)];
        st[c] = __builtin_amdgcn_mfma_f32_32x32x16_bf16(kf, qf[ks], st[c], 0, 0, 0);
      }
    }
    __builtin_amdgcn_s_setprio(0);

    // ---- scale + causal mask (diagonal tile only) ----
    const bool diag = (tt == qt);
#pragma unroll
    for (int c = 0; c < 2; ++c)
#pragma unroll
      for (int r = 0; r < 16; ++r) {
        float sv = st[c][r] * 0.125f;
        if (diag) {
          int kvg = kv0 + c * 32 + (r & 3) + 8 * (r >> 2) + 4 * h;
          sv = (kvg <= qg) ? sv : -1e30f;
        }
        st[c][r] = sv;
      }

    // ---- online softmax: per-lane scalar m/l ----
    float mt = st[0][0];
#pragma unroll
    for (int c = 0; c < 2; ++c)
#pragma unroll
      for (int r = 0; r < 16; ++r) mt = fmaxf(mt, st[c][r]);
    mt = fmaxf(mt, __int_as_float(__shfl_xor(__float_as_int(mt), 32, 64)));

    if (!__all(mt <= mrun + 8.0f)) {     // T13 defer-max
      float mnew = fmaxf(mrun, mt);
      float corr = __expf(mrun - mnew);
      lrun *= corr;
#pragma unroll
      for (int n = 0; n < 2; ++n)
#pragma unroll
        for (int r = 0; r < 16; ++r) ot[n][r] *= corr;
      mrun = mnew;
    }

    float ls = 0.f;
#pragma unroll
    for (int c = 0; c < 2; ++c)
#pragma unroll
      for (int r = 0; r < 16; ++r) {
        float p = __expf(st[c][r] - mrun);
        st[c][r] = p;
        ls += p;
      }
    ls += __int_as_float(__shfl_xor(__float_as_int(ls), 32, 64));
    lrun += ls;

    // ---- PV: O^T += V^T * P (pack bf16 + half-swap inline) ----
#pragma unroll
    for (int kst = 0; kst < 4; ++kst) {
      const int c = kst >> 1, k1 = kst & 1;
      u32 pkg[4];
#pragma unroll
      for (int g4 = 0; g4 < 4; ++g4)
        pkg[g4] = cvtpk_bf16(st[c][2 * (4 * k1 + g4)], st[c][2 * (4 * k1 + g4) + 1]);
      u32 w[4];
#pragma unroll
      for (int par = 0; par < 2; ++par) {
        u32 x = pkg[par];
        u32 y = pkg[2 + par];
        u32 tt2 = h ? x : y;
        u32 tp = (u32)__shfl_xor((int)tt2, 32, 64);
        w[par]     = h ? tp : x;
        w[par + 2] = h ? y : tp;
      }
      union { u32 u[4]; bf16x8 v; } pb;
      pb.u[0] = w[0]; pb.u[1] = w[1]; pb.u[2] = w[2]; pb.u[3] = w[3];
      __builtin_amdgcn_s_setprio(1);
#pragma unroll
      for (int n = 0; n < 2; ++n) {
        bf16x8 vf = *(const bf16x8*)&lvb[((n << 5) + ql) * 64 + (((2 * kst + h) ^ swz) << 3)];
        ot[n] = __builtin_amdgcn_mfma_f32_32x32x16_bf16(vf, pb.v, ot[n], 0, 0, 0);
      }
      __builtin_amdgcn_s_setprio(0);
    }
  }

  // ---- flash-combine of 4 pair-partials (reuse staging LDS) ----
  __syncthreads();                       // all pairs done with K/V LDS
  {
    float* comb = (float*)lds_kv[pair];  // 64 d x 64 q f32, q swizzled by d
#pragma unroll
    for (int n = 0; n < 2; ++n)
#pragma unroll
      for (int r = 0; r < 16; ++r) {
        int d = 32 * n + (r & 3) + 8 * (r >> 2) + 4 * h;
        comb[d * 64 + (qq ^ ((d & 7) << 3))] = ot[n][r];
      }
    if (h == 0) { lds_ml[pair][qq][0] = mrun; lds_ml[pair][qq][1] = lrun; }
  }
  __syncthreads();
  {
    const int q = tid >> 3;
    const int d0 = (tid & 7) * 8;
    float m0 = lds_ml[0][q][0], m1 = lds_ml[1][q][0];
    float m2 = lds_ml[2][q][0], m3 = lds_ml[3][q][0];
    float mg = fmaxf(fmaxf(m0, m1), fmaxf(m2, m3));
    float w0 = __expf(m0 - mg), w1 = __expf(m1 - mg);
    float w2 = __expf(m2 - mg), w3 = __expf(m3 - mg);
    float lsum = w0 * lds_ml[0][q][1] + w1 * lds_ml[1][q][1]
               + w2 * lds_ml[2][q][1] + w3 * lds_ml[3][q][1];
    float inv = 1.0f / lsum;
    const float* c0 = (const float*)lds_kv[0];
    const float* c1 = (const float*)lds_kv[1];
    const float* c2 = (const float*)lds_kv[2];
    const float* c3 = (const float*)lds_kv[3];
    u32 o4[4];
#pragma unroll
    for (int ii = 0; ii < 4; ++ii) {
      int da = d0 + 2 * ii, db = da + 1;
      int ia = da * 64 + (q ^ ((da & 7) << 3));
      int ib = db * 64 + (q ^ ((db & 7) << 3));
      float va = w0 * c0[ia] + w1 * c1[ia] + w2 * c2[ia] + w3 * c3[ia];
      float vb = w0 * c0[ib] + w1 * c1[ib] + w2 * c2[ib] + w3 * c3[ib];
      o4[ii] = cvtpk_bf16(va * inv, vb * inv);
    }
    uint4 outv;
    outv.x = o4[0]; outv.y = o4[1]; outv.z = o4[2]; outv.w = o4[3];
    *(uint4*)&AO[baseQK + (size_t)(q0 + q) * DM + d0] = outv;
  }
#undef STAGE_PAIR
}

extern "C" void kernel_launch(void* const* d_in, const int* in_sizes, int n_in,
                              void* d_out, int out_size, void* d_ws, size_t ws_size,
                              hipStream_t stream) {
  const float* q  = (const float*)d_in[0];
  const float* k  = (const float*)d_in[1];
  const float* v  = (const float*)d_in[2];
  // d_in[3] = mask : deterministic causal tril, applied analytically
  const float* wq = (const float*)d_in[4];
  const float* wk = (const float*)d_in[5];
  const float* wv = (const float*)d_in[6];
  const float* wo = (const float*)d_in[7];

  const size_t nIn = (size_t)MS * DM;
  const size_t nW  = (size_t)DM * DM;

  u16* ws = (u16*)d_ws;
  u16* qb  = ws; ws += nIn;
  u16* kb  = ws; ws += nIn;
  u16* vb  = ws; ws += nIn;
  u16* wqb = ws; ws += nW;
  u16* wkb = ws; ws += nW;
  u16* wvb = ws; ws += nW;
  u16* wob = ws; ws += nW;
  u16* Qp  = ws; ws += nIn;
  u16* Kp  = ws; ws += nIn;
  u16* Vt  = ws; ws += nIn;   // [DM][MS] transposed V projection
  u16* AO  = ws; ws += nIn;

  CvtArgs ca;
  ca.src[0] = q;  ca.dst[0] = qb;  ca.n4[0] = (int)(nIn / 4);
  ca.src[1] = k;  ca.dst[1] = kb;  ca.n4[1] = (int)(nIn / 4);
  ca.src[2] = v;  ca.dst[2] = vb;  ca.n4[2] = (int)(nIn / 4);
  ca.src[3] = wq; ca.dst[3] = wqb; ca.n4[3] = (int)(nW / 4);
  ca.src[4] = wk; ca.dst[4] = wkb; ca.n4[4] = (int)(nW / 4);
  ca.src[5] = wv; ca.dst[5] = wvb; ca.n4[5] = (int)(nW / 4);
  ca.src[6] = wo; ca.dst[6] = wob; ca.n4[6] = (int)(nW / 4);
  cvt_all<<<dim3(256, 7), 256, 0, stream>>>(ca);

  gemm_bt<true,64><<<dim3(8, 64), 256, 0, stream>>>(qb, wqb, Qp, MS, DM, DM);
  gemm_bt<true,64><<<dim3(8, 64), 256, 0, stream>>>(kb, wkb, Kp, MS, DM, DM);
  // V^T = Wv * X^T  -> [DM][MS], the layout attention wants
  gemm_bt<true,64><<<dim3(32, 16), 256, 0, stream>>>(wvb, vb, Vt, DM, MS, DM);

  attn_fwd<<<dim3(NQ * 32), 512, 0, stream>>>(Qp, Kp, Vt, AO);

  gemm_bt<false,64><<<dim3(8, 64), 256, 0, stream>>>(AO, wob, d_out, MS, DM, DM);
}